// Round 9
// baseline (456.062 us; speedup 1.0000x reference)
//
#include <hip/hip_runtime.h>

#define DEV __device__ __forceinline__

typedef unsigned short u16;
typedef __bf16 bf16x8 __attribute__((ext_vector_type(8)));
typedef float f32x4 __attribute__((ext_vector_type(4)));

// ---------- helpers ----------
static DEV u16 f2bf(float f) {
    union { float f; unsigned u; } v; v.f = f;
    unsigned r = v.u + 0x7fffu + ((v.u >> 16) & 1u);  // RNE
    return (u16)(r >> 16);
}
static DEV float bf2f(u16 u) {
    union { unsigned u; float f; } v; v.u = ((unsigned)u) << 16;
    return v.f;
}
static DEV void g2l16(const u16* g, u16* l) {
    __builtin_amdgcn_global_load_lds(
        (const __attribute__((address_space(1))) void*)g,
        (__attribute__((address_space(3))) void*)l, 16, 0, 0);
}

#define BAR()    do { __builtin_amdgcn_s_barrier(); __builtin_amdgcn_sched_barrier(0); } while (0)
#define WAITV(N) asm volatile("s_waitcnt vmcnt(" #N ")" ::: "memory")

// 16 MFMAs = one C-quadrant (4 M-frags x 2 N-frags) x K=64. Static acc idx.
#define MM16(A, B, FMO, FNO) do {                                            \
    __builtin_amdgcn_s_setprio(1);                                           \
    _Pragma("unroll")                                                        \
    for (int fm_ = 0; fm_ < 4; ++fm_)                                        \
      _Pragma("unroll")                                                      \
      for (int fn_ = 0; fn_ < 2; ++fn_)                                      \
        _Pragma("unroll")                                                    \
        for (int ks_ = 0; ks_ < 2; ++ks_)                                    \
          acc[(FMO) + fm_][(FNO) + fn_] = __builtin_amdgcn_mfma_f32_16x16x32_bf16( \
              A[fm_][ks_], B[fn_][ks_], acc[(FMO) + fm_][(FNO) + fn_], 0, 0, 0); \
    __builtin_amdgcn_s_setprio(0);                                           \
} while (0)

// dims: B*S = 4096 rows, D = 2048, M = 5632, E = 8, R = 16, scaling = 2.0

// ---------- K0: fused prep = router/Ag/Au projections (blocks 0-511)
//                          + weight f32->bf16 conversion (blocks 512+) ----------
// Router blocks are VALU/latency-bound; conv blocks are HBM-BW-bound. Fused in one
// grid so router time hides under conv's BW stream (they touch disjoint inputs).
__global__ __launch_bounds__(256) void k_prep(
    const float* __restrict__ x, const float* __restrict__ Wr,
    const float* __restrict__ Ag, const float* __restrict__ Au,
    const float* __restrict__ Wg, const float* __restrict__ Wu, const float* __restrict__ Wd,
    const float* __restrict__ Bg, const float* __restrict__ Bu, const float* __restrict__ Bd,
    u16* __restrict__ x16, float* __restrict__ fin1,
    u16* __restrict__ Wg16, u16* __restrict__ Wu16, u16* __restrict__ Wd16,
    u16* __restrict__ Bgx, u16* __restrict__ Bux, u16* __restrict__ Bdx)
{
    __shared__ float xs[64][65];
    __shared__ float wsm[40][64];
    const int bid = blockIdx.x;
    const int t = threadIdx.x;

    if (bid < 512) {
        // ---- router part: rb = bid&63, ksp = bid>>6 ----
        const int rb = bid & 63, ksp = bid >> 6;
        const int row0 = rb * 64;
        const int rloc = t & 63, og = t >> 6;
        float acc[10];
#pragma unroll
        for (int o = 0; o < 10; ++o) acc[o] = 0.f;

        for (int c4 = 0; c4 < 4; ++c4) {
            const int k0 = ksp * 256 + c4 * 64;
            __syncthreads();
#pragma unroll
            for (int i = 0; i < 4; ++i) {
                int idx = t + i * 256;
                int r = idx >> 4, c = (idx & 15) * 4;
                float4 v = *(const float4*)&x[(size_t)(row0 + r) * 2048 + k0 + c];
                xs[r][c + 0] = v.x; xs[r][c + 1] = v.y; xs[r][c + 2] = v.z; xs[r][c + 3] = v.w;
                ushort4 o4; o4.x = f2bf(v.x); o4.y = f2bf(v.y); o4.z = f2bf(v.z); o4.w = f2bf(v.w);
                *(ushort4*)&x16[(size_t)(row0 + r) * 2048 + k0 + c] = o4;
            }
#pragma unroll
            for (int i = 0; i < 3; ++i) {
                int idx = t + i * 256;
                if (idx < 640) {
                    int r = idx >> 4, c = (idx & 15) * 4;
                    const float* src = (r < 8) ? (Wr + (size_t)r * 2048)
                                    : (r < 24) ? (Ag + (size_t)(r - 8) * 2048)
                                               : (Au + (size_t)(r - 24) * 2048);
                    float4 v = *(const float4*)&src[k0 + c];
                    wsm[r][c + 0] = v.x; wsm[r][c + 1] = v.y; wsm[r][c + 2] = v.z; wsm[r][c + 3] = v.w;
                }
            }
            __syncthreads();
#pragma unroll
            for (int k = 0; k < 64; ++k) {
                float xv = xs[rloc][k];
#pragma unroll
                for (int o = 0; o < 10; ++o) acc[o] += xv * wsm[og * 10 + o][k];
            }
        }
        float* dst = fin1 + ((size_t)ksp * 4096 + row0 + rloc) * 40 + og * 10;
#pragma unroll
        for (int o = 0; o < 10; ++o) dst[o] = acc[o];
        return;
    }

    // ---- conv part ----
    const long long NW = 2883584;  // 5632*2048/4
    const long long NB = 180224;   // 5632*128/4
    const long long ND = 65536;    // 2048*128/4
    long long gid = (long long)(bid - 512) * 256 + t;
    if (gid < 3 * NW) {
        const float* s; u16* d; long long g = gid;
        if (g < NW)           { s = Wg; d = Wg16; }
        else if (g < 2 * NW)  { s = Wu; d = Wu16; g -= NW; }
        else                  { s = Wd; d = Wd16; g -= 2 * NW; }
        float4 v = *(const float4*)(s + g * 4);
        ushort4 o; o.x = f2bf(v.x); o.y = f2bf(v.y); o.z = f2bf(v.z); o.w = f2bf(v.w);
        *(ushort4*)(d + g * 4) = o;
    } else {
        long long g = gid - 3 * NW;
        const float* s; u16* d; int nr;
        if (g < NB)               { s = Bg; d = Bgx; nr = 5632; }
        else if (g < 2 * NB)      { s = Bu; d = Bux; nr = 5632; g -= NB; }
        else if (g < 2 * NB + ND) { s = Bd; d = Bdx; nr = 2048; g -= 2 * NB; }
        else return;
        int n = (int)(g >> 5);
        int j0 = ((int)g & 31) * 4;     // j0 = e*16 + r0
        int e = j0 >> 4, r0 = j0 & 15;
        float4 v = *(const float4*)&s[((size_t)e * nr + n) * 16 + r0];
        ushort4 o; o.x = f2bf(v.x); o.y = f2bf(v.y); o.z = f2bf(v.z); o.w = f2bf(v.w);
        *(ushort4*)&d[(size_t)n * 128 + j0] = o;
    }
}

// ---------- K1b: softmax/argmax/expert_choice + hwg/hwu ----------
__global__ __launch_bounds__(64) void k_fin1(
    const float* __restrict__ fin1, const float* __restrict__ br,
    float* __restrict__ routing_ws, float* __restrict__ out_rt, float* __restrict__ out_ec,
    u16* __restrict__ hwg, u16* __restrict__ hwu)
{
    const int row = blockIdx.x * 64 + threadIdx.x;
    float s[40];
#pragma unroll
    for (int j = 0; j < 40; ++j) s[j] = 0.f;
    for (int p = 0; p < 8; ++p) {
        const float* src = fin1 + ((size_t)p * 4096 + row) * 40;
#pragma unroll
        for (int j = 0; j < 40; ++j) s[j] += src[j];
    }
    float lg[8]; float m = -1e30f;
#pragma unroll
    for (int e = 0; e < 8; ++e) { lg[e] = s[e] + br[e]; m = fmaxf(m, lg[e]); }
    float ex[8]; float sum = 0.f;
#pragma unroll
    for (int e = 0; e < 8; ++e) { ex[e] = expf(lg[e] - m); sum += ex[e]; }
    float r8[8];
#pragma unroll
    for (int e = 0; e < 8; ++e) r8[e] = ex[e] / sum;
    int best = 0;
#pragma unroll
    for (int e = 1; e < 8; ++e) if (r8[e] > r8[best]) best = e;
#pragma unroll
    for (int e = 0; e < 8; ++e) {
        routing_ws[(size_t)row * 8 + e] = r8[e];
        out_rt[(size_t)row * 8 + e] = r8[e];
        float yh = (e == best) ? 1.f : 0.f;
        out_ec[(size_t)row * 8 + e] = (yh - r8[e]) + r8[e];
    }
#pragma unroll
    for (int e = 0; e < 8; ++e) {
        float re = r8[e];
#pragma unroll
        for (int rk = 0; rk < 16; ++rk) {
            hwg[(size_t)row * 128 + e * 16 + rk] = f2bf(2.f * s[8 + rk] * re);
            hwu[(size_t)row * 128 + e * 16 + rk] = f2bf(2.f * s[24 + rk] * re);
        }
    }
}

// ---------- 256x256 GEMM (r6 schedule, direct-store epilogues) ----------
// C = A[*,K] @ B[*,K]^T. MODE 0 (down): z = K-split; f32 out. MODE 1: z = gate|up; bf16 out.
// LDS (u16 idx): A buf0 @0, buf1 @16384; B buf0 @32768, buf1 @49152.
// Swizzle: global[r][c] stored at LDS[r][c ^ ((r&7)<<3)] (u16), via pre-swizzled source col.
template<int MODE>
__global__ __launch_bounds__(512, 2) void k_gemm8(
    const u16* __restrict__ A0, int lda0,
    const u16* __restrict__ A1g, const u16* __restrict__ A1u,
    const u16* __restrict__ B0g, int ldb0, const u16* __restrict__ B0u,
    const u16* __restrict__ B1g, const u16* __restrict__ B1u,
    int Ksplit,
    float* __restrict__ outF0, float* __restrict__ outF1,
    u16* __restrict__ outHg, u16* __restrict__ outHu,
    int nbm, int nbn)
{
    __shared__ u16 lds[65536];   // 128 KiB
    const int t = threadIdx.x;
    const int nwg = (int)gridDim.x;
    const int orig = (int)blockIdx.x;
    const int sw = (orig & 7) * (nwg >> 3) + (orig >> 3);   // XCD swizzle (nwg%8==0)
    const int bm = sw % nbm; const int rest = sw / nbm;
    const int bn = rest % nbn; const int z = rest / nbn;

    const int row0 = bm * 256, col0 = bn * 256;
    int ktb, ntl;
    if (MODE == 0) { ktb = z ? 46 : 0; ntl = z ? 44 : 46; }  // ktb even, ntl even
    else           { ktb = 0;          ntl = 34; }
    const int kend = ktb + ntl;
    const u16* A1 = (MODE == 1 && z) ? A1u : A1g;
    const u16* B0 = (MODE == 1 && z) ? B0u : B0g;
    const u16* B1 = (MODE == 1 && z) ? B1u : B1g;

    const int lane = t & 63, lr = lane & 15, lg = lane >> 4;
    const int wid = t >> 6, wr = wid >> 2, wcol = wid & 3;
    const int arow = wr * 128 + lr;          // + fm*16
    const int brow = wcol * 64 + lr;         // + fn*16
    const int sa = (arow & 7) << 3;          // read-swizzle XOR (u16 units)
    const int sb = (brow & 7) << 3;

    // ---- staging: per-thread bases computed ONCE; per-call offset is wave-uniform ----
    const int rA = t >> 3;                                  // staging row-in-tile (h=0,j=0)
    const int c00u = ((t & 7) * 8) ^ ((rA & 7) << 3);       // pre-swizzled col (u16)
    const u16* bA0 = A0 + (size_t)(row0 + rA) * lda0 + c00u;
    const u16* bA1 = A1 + ((size_t)(row0 + rA) << 7) + c00u;
    const u16* bB0 = B0 + (size_t)(col0 + rA) * ldb0 + c00u;
    const u16* bB1 = B1 + ((size_t)(col0 + rA) << 7) + c00u;
    const int ldsT = t * 8;                                 // u16 units

    auto stgA = [&](int kt, int h, int bufu) {   // h, bufu literal at call sites
        const int k0 = kt * 64;
        const bool p2 = (k0 >= Ksplit);
        const u16* b = p2 ? (bA1 + (k0 - Ksplit)) : (bA0 + k0);
        const size_t ld = p2 ? (size_t)128 : (size_t)lda0;
        g2l16(b + (size_t)(h * 128) * ld,      &lds[bufu + h * 8192 + ldsT]);
        g2l16(b + (size_t)(h * 128 + 64) * ld, &lds[bufu + h * 8192 + 4096 + ldsT]);
    };
    auto stgB = [&](int kt, int h, int bufu) {
        const int k0 = kt * 64;
        const bool p2 = (k0 >= Ksplit);
        const u16* b = p2 ? (bB1 + (k0 - Ksplit)) : (bB0 + k0);
        const size_t ld = p2 ? (size_t)128 : (size_t)ldb0;
        g2l16(b + (size_t)(h * 128) * ld,      &lds[32768 + bufu + h * 8192 + ldsT]);
        g2l16(b + (size_t)(h * 128 + 64) * ld, &lds[32768 + bufu + h * 8192 + 4096 + ldsT]);
    };
    auto rdA = [&](int bufu, int fb, bf16x8 (&d)[4][2]) {
#pragma unroll
        for (int fm = 0; fm < 4; ++fm)
#pragma unroll
            for (int ks = 0; ks < 2; ++ks)
                d[fm][ks] = *(const bf16x8*)&lds[bufu + (arow + (fb + fm) * 16) * 64
                                                 + (((ks << 5) | (lg << 3)) ^ sa)];
    };
    auto rdB = [&](int bufu, int fb, bf16x8 (&d)[2][2]) {
#pragma unroll
        for (int fn = 0; fn < 2; ++fn)
#pragma unroll
            for (int ks = 0; ks < 2; ++ks)
                d[fn][ks] = *(const bf16x8*)&lds[32768 + bufu + (brow + (fb + fn) * 16) * 64
                                                 + (((ks << 5) | (lg << 3)) ^ sb)];
    };

    f32x4 acc[8][4];
    const f32x4 zf = {0.f, 0.f, 0.f, 0.f};
#pragma unroll
    for (int i = 0; i < 8; ++i)
#pragma unroll
        for (int j = 0; j < 4; ++j) acc[i][j] = zf;

    // prologue: A(ktb),B(ktb) -> buf0; B(ktb+1) -> buf1
    stgA(ktb, 0, 0); stgA(ktb, 1, 0);
    stgB(ktb, 0, 0); stgB(ktb, 1, 0);
    stgB(ktb + 1, 0, 16384); stgB(ktb + 1, 1, 16384);
    WAITV(4);              // buf0 landed; B(ktb+1) (4 loads) in flight
    BAR();

    const int ni = ntl >> 1;
    for (int i = 0; i < ni; ++i) {
        const int kt0 = ktb + 2 * i, kt1 = kt0 + 1;
        const bool s2 = (kt0 + 2 < kend), s3 = (kt1 + 2 < kend);  // TT or FF (ntl even)
        bf16x8 alo[4][2], ahi[4][2], b01[2][2], b23[2][2];
        // R1: Q0+Q1 of kt0 (buf0) | stage A(kt1)->buf1
        rdA(0, 0, alo); rdB(0, 0, b01); rdB(0, 2, b23);
        stgA(kt1, 0, 16384); stgA(kt1, 1, 16384);
        BAR();
        MM16(alo, b01, 0, 0); MM16(alo, b23, 0, 2);
        BAR();
        // R2: Q2+Q3 of kt0 | stage B(kt0+2)->buf0 | end: wait buf1 (B kt1 + A kt1) landed
        rdA(0, 4, ahi);
        if (s2) { stgB(kt0 + 2, 0, 0); stgB(kt0 + 2, 1, 0); }
        BAR();
        MM16(ahi, b01, 4, 0); MM16(ahi, b23, 4, 2);
        if (s2) { WAITV(4); } else { WAITV(0); }
        BAR();
        // R3: Q0+Q1 of kt1 (buf1) | stage A(kt0+2)->buf0
        rdA(16384, 0, alo); rdB(16384, 0, b01); rdB(16384, 2, b23);
        if (s2) { stgA(kt0 + 2, 0, 0); stgA(kt0 + 2, 1, 0); }
        BAR();
        MM16(alo, b01, 0, 0); MM16(alo, b23, 0, 2);
        BAR();
        // R4: Q2+Q3 of kt1 | stage B(kt1+2)->buf1 | end: wait buf0 (B,A of kt0+2) landed
        rdA(16384, 4, ahi);
        if (s3) { stgB(kt1 + 2, 0, 16384); stgB(kt1 + 2, 1, 16384); }
        BAR();
        MM16(ahi, b01, 4, 0); MM16(ahi, b23, 4, 2);
        if (s3) { WAITV(4); }
        BAR();
    }

    // epilogue: C/D layout col = lane&15, row = (lane>>4)*4 + j  [m89-verified]
#pragma unroll
    for (int fm = 0; fm < 8; ++fm) {
#pragma unroll
        for (int fn = 0; fn < 4; ++fn) {
            const int r = row0 + wr * 128 + fm * 16 + lg * 4;
            const int c = col0 + wcol * 64 + fn * 16 + lr;
            f32x4 v = acc[fm][fn];
            if constexpr (MODE == 0) {
                float* out = z ? outF1 : outF0;
#pragma unroll
                for (int j = 0; j < 4; ++j) out[(size_t)(r + j) * 2048 + c] = v[j];
            } else {
                u16* out = z ? outHu : outHg;
#pragma unroll
                for (int j = 0; j < 4; ++j) out[(size_t)(r + j) * 5632 + c] = f2bf(v[j]);
            }
        }
    }
}

// ---------- K5: fused SwiGLU + hd projection ----------
__global__ __launch_bounds__(256) void k_hd(
    u16* __restrict__ g, const u16* __restrict__ u,
    const float* __restrict__ Ad, float* __restrict__ fin2)
{
    __shared__ float hs[64][65];
    __shared__ float as2[16][64];
    const int rb = blockIdx.x, ksp = blockIdx.y;
    const int row0 = rb * 64;
    const int t = threadIdx.x;
    const int rloc = t & 63, og = t >> 6;
    float acc[4] = {0.f, 0.f, 0.f, 0.f};
    for (int c4 = 0; c4 < 8; ++c4) {
        const int k0 = ksp * 512 + c4 * 64;
        __syncthreads();
#pragma unroll
        for (int i = 0; i < 4; ++i) {
            int idx = t + i * 256;
            int r = idx >> 4, cc = (idx & 15) * 4;
            size_t go = (size_t)(row0 + r) * 5632 + k0 + cc;
            ushort4 gv = *(const ushort4*)&g[go];
            ushort4 uv = *(const ushort4*)&u[go];
            float h0, h1, h2, h3;
            { float gg = bf2f(gv.x); h0 = gg / (1.f + __expf(-gg)) * bf2f(uv.x); }
            { float gg = bf2f(gv.y); h1 = gg / (1.f + __expf(-gg)) * bf2f(uv.y); }
            { float gg = bf2f(gv.z); h2 = gg / (1.f + __expf(-gg)) * bf2f(uv.z); }
            { float gg = bf2f(gv.w); h3 = gg / (1.f + __expf(-gg)) * bf2f(uv.w); }
            hs[r][cc + 0] = h0; hs[r][cc + 1] = h1; hs[r][cc + 2] = h2; hs[r][cc + 3] = h3;
            ushort4 hv; hv.x = f2bf(h0); hv.y = f2bf(h1); hv.z = f2bf(h2); hv.w = f2bf(h3);
            *(ushort4*)&g[go] = hv;   // h overwrites gate (block-local 1:1, safe)
        }
        {
            int r = t >> 4, cc = (t & 15) * 4;
            float4 w = *(const float4*)&Ad[(size_t)r * 5632 + k0 + cc];
            as2[r][cc + 0] = w.x; as2[r][cc + 1] = w.y; as2[r][cc + 2] = w.z; as2[r][cc + 3] = w.w;
        }
        __syncthreads();
#pragma unroll
        for (int k = 0; k < 64; ++k) {
            float hv = hs[rloc][k];
#pragma unroll
            for (int o = 0; o < 4; ++o) acc[o] += hv * as2[og * 4 + o][k];
        }
    }
    float* dst = fin2 + ((size_t)ksp * 4096 + row0 + rloc) * 16 + og * 4;
#pragma unroll
    for (int o = 0; o < 4; ++o) dst[o] = acc[o];
}

// ---------- K5b: hwd = 2 * hd ⊗ routing (bf16) ----------
__global__ __launch_bounds__(64) void k_fin2(
    const float* __restrict__ fin2, const float* __restrict__ routing_ws, u16* __restrict__ hwd)
{
    const int row = blockIdx.x * 64 + threadIdx.x;
    float hd[16];
#pragma unroll
    for (int j = 0; j < 16; ++j) hd[j] = 0.f;
    for (int p = 0; p < 11; ++p) {
        const float* src = fin2 + ((size_t)p * 4096 + row) * 16;
#pragma unroll
        for (int j = 0; j < 16; ++j) hd[j] += src[j];
    }
#pragma unroll
    for (int e = 0; e < 8; ++e) {
        float re = routing_ws[(size_t)row * 8 + e];
#pragma unroll
        for (int rk = 0; rk < 16; ++rk)
            hwd[(size_t)row * 128 + e * 16 + rk] = f2bf(2.f * hd[rk] * re);
    }
}

// ---------- K7: out += split-K partial ----------
__global__ __launch_bounds__(256) void k_reduce(
    float* __restrict__ o, const float* __restrict__ p1)
{
    size_t i = ((size_t)blockIdx.x * 256 + threadIdx.x) * 4;
    float4 a = *(const float4*)&o[i];
    float4 b = *(const float4*)&p1[i];
    float4 r; r.x = a.x + b.x; r.y = a.y + b.y; r.z = a.z + b.z; r.w = a.w + b.w;
    *(float4*)&o[i] = r;
}

// ---------- launch ----------
extern "C" void kernel_launch(void* const* d_in, const int* in_sizes, int n_in,
                              void* d_out, int out_size, void* d_ws, size_t ws_size,
                              hipStream_t stream)
{
    (void)in_sizes; (void)n_in; (void)out_size; (void)ws_size;
    const float* x  = (const float*)d_in[0];
    const float* Wr = (const float*)d_in[1];
    const float* br = (const float*)d_in[2];
    const float* Wg = (const float*)d_in[3];
    const float* Wu = (const float*)d_in[4];
    const float* Wd = (const float*)d_in[5];
    const float* Ag = (const float*)d_in[6];
    const float* Au = (const float*)d_in[7];
    const float* Ad = (const float*)d_in[8];
    const float* Bg = (const float*)d_in[9];
    const float* Bu = (const float*)d_in[10];
    const float* Bd = (const float*)d_in[11];

    float* outp   = (float*)d_out;            // [4096, 2048]
    float* out_rt = outp + 8388608;           // [4096, 8]
    float* out_ec = out_rt + 32768;           // [4096, 8]

    char* p = (char*)d_ws;
    auto carve = [&](size_t n) -> char* { char* r = p; p += (n + 255) & ~(size_t)255; return r; };
    u16*   x16        = (u16*)carve(16777216);   // [4096,2048] bf16
    u16*   hwg        = (u16*)carve(1048576);    // [4096,128]
    u16*   hwu        = (u16*)carve(1048576);
    u16*   hwd        = (u16*)carve(1048576);
    float* routing_ws = (float*)carve(131072);   // [4096,8]
    float* fin1       = (float*)carve(5242880);  // [8][4096][40]
    float* fin2       = (float*)carve(2883584);  // [11][4096][16]
    u16*   Wg16       = (u16*)carve(23068672);   // [5632,2048]
    u16*   Wu16       = (u16*)carve(23068672);
    u16*   Wd16       = (u16*)carve(23068672);   // [2048,5632]
    u16*   Bgx        = (u16*)carve(1441792);    // [5632,128]
    u16*   Bux        = (u16*)carve(1441792);
    u16*   Bdx        = (u16*)carve(524288);     // [2048,128]
    u16*   gbuf       = (u16*)carve(46137344);   // [4096,5632] gate -> h (in place)
    u16*   ubuf       = (u16*)carve(46137344);   // [4096,5632] up; later f32 partial
    float* part1      = (float*)ubuf;            // [4096,2048] f32 split-K partial (aliases ubuf)

    // fused prep: blocks 0-511 router (+x16), 512..35967 conv
    k_prep<<<dim3(35968), dim3(256), 0, stream>>>(
        x, Wr, Ag, Au, Wg, Wu, Wd, Bg, Bu, Bd,
        x16, fin1, Wg16, Wu16, Wd16, Bgx, Bux, Bdx);
    k_fin1<<<dim3(64), dim3(64), 0, stream>>>(fin1, br, routing_ws, out_rt, out_ec, hwg, hwu);
    // gate|up: C[z] = [x|hw z] @ [W z|B z]^T, K = 2048+128, 16x22x2 = 704 blocks
    k_gemm8<1><<<dim3(704), dim3(512), 0, stream>>>(
        x16, 2048, hwg, hwu, Wg16, 2048, Wu16, Bgx, Bux,
        2048, (float*)nullptr, (float*)nullptr, gbuf, ubuf, 16, 22);
    k_hd<<<dim3(64, 11), dim3(256), 0, stream>>>(gbuf, ubuf, Ad, fin2);
    k_fin2<<<dim3(64), dim3(64), 0, stream>>>(fin2, routing_ws, hwd);
    // down: out = [h|hwd] @ [Wd|Bdx]^T, K = 5632+128, split-K z: 46/44 tiles, 256 blocks
    k_gemm8<0><<<dim3(256), dim3(512), 0, stream>>>(
        gbuf, 5632, hwd, hwd, Wd16, 5632, Wd16, Bdx, Bdx,
        5632, outp, part1, (u16*)nullptr, (u16*)nullptr, 16, 8);
    k_reduce<<<dim3(8192), dim3(256), 0, stream>>>(outp, part1);
}

// Round 10
// 431.826 us; speedup vs baseline: 1.0561x; 1.0561x over previous
//
#include <hip/hip_runtime.h>

#define DEV __device__ __forceinline__

typedef unsigned short u16;
typedef __bf16 bf16x8 __attribute__((ext_vector_type(8)));
typedef float f32x4 __attribute__((ext_vector_type(4)));

// ---------- helpers ----------
static DEV u16 f2bf(float f) {
    union { float f; unsigned u; } v; v.f = f;
    unsigned r = v.u + 0x7fffu + ((v.u >> 16) & 1u);  // RNE
    return (u16)(r >> 16);
}
static DEV float bf2f(u16 u) {
    union { unsigned u; float f; } v; v.u = ((unsigned)u) << 16;
    return v.f;
}
static DEV void g2l16(const u16* g, u16* l) {
    __builtin_amdgcn_global_load_lds(
        (const __attribute__((address_space(1))) void*)g,
        (__attribute__((address_space(3))) void*)l, 16, 0, 0);
}

#define BAR()    do { __builtin_amdgcn_s_barrier(); __builtin_amdgcn_sched_barrier(0); } while (0)
#define WAITV(N) asm volatile("s_waitcnt vmcnt(" #N ")" ::: "memory")

// 16 MFMAs = one C-quadrant (4 M-frags x 2 N-frags) x K=64. Static acc idx.
#define MM16(A, B, FMO, FNO) do {                                            \
    __builtin_amdgcn_s_setprio(1);                                           \
    _Pragma("unroll")                                                        \
    for (int fm_ = 0; fm_ < 4; ++fm_)                                        \
      _Pragma("unroll")                                                      \
      for (int fn_ = 0; fn_ < 2; ++fn_)                                      \
        _Pragma("unroll")                                                    \
        for (int ks_ = 0; ks_ < 2; ++ks_)                                    \
          acc[(FMO) + fm_][(FNO) + fn_] = __builtin_amdgcn_mfma_f32_16x16x32_bf16( \
              A[fm_][ks_], B[fn_][ks_], acc[(FMO) + fm_][(FNO) + fn_], 0, 0, 0); \
    __builtin_amdgcn_s_setprio(0);                                           \
} while (0)

// dims: B*S = 4096 rows, D = 2048, M = 5632, E = 8, R = 16, scaling = 2.0

// ---------- K2: weight f32 -> bf16 conversion + LoRA-B repack ----------
__global__ __launch_bounds__(256) void k_conv(
    const float* __restrict__ Wg, const float* __restrict__ Wu, const float* __restrict__ Wd,
    const float* __restrict__ Bg, const float* __restrict__ Bu, const float* __restrict__ Bd,
    u16* __restrict__ Wg16, u16* __restrict__ Wu16, u16* __restrict__ Wd16,
    u16* __restrict__ Bgx, u16* __restrict__ Bux, u16* __restrict__ Bdx)
{
    const long long NW = 2883584;  // 5632*2048/4
    const long long NB = 180224;   // 5632*128/4
    const long long ND = 65536;    // 2048*128/4
    long long gid = (long long)blockIdx.x * 256 + threadIdx.x;
    if (gid < 3 * NW) {
        const float* s; u16* d; long long g = gid;
        if (g < NW)           { s = Wg; d = Wg16; }
        else if (g < 2 * NW)  { s = Wu; d = Wu16; g -= NW; }
        else                  { s = Wd; d = Wd16; g -= 2 * NW; }
        float4 v = *(const float4*)(s + g * 4);
        ushort4 o; o.x = f2bf(v.x); o.y = f2bf(v.y); o.z = f2bf(v.z); o.w = f2bf(v.w);
        *(ushort4*)(d + g * 4) = o;
    } else {
        long long g = gid - 3 * NW;
        const float* s; u16* d; int nr;
        if (g < NB)               { s = Bg; d = Bgx; nr = 5632; }
        else if (g < 2 * NB)      { s = Bu; d = Bux; nr = 5632; g -= NB; }
        else if (g < 2 * NB + ND) { s = Bd; d = Bdx; nr = 2048; g -= 2 * NB; }
        else return;
        int n = (int)(g >> 5);
        int j0 = ((int)g & 31) * 4;     // j0 = e*16 + r0
        int e = j0 >> 4, r0 = j0 & 15;
        float4 v = *(const float4*)&s[((size_t)e * nr + n) * 16 + r0];
        ushort4 o; o.x = f2bf(v.x); o.y = f2bf(v.y); o.z = f2bf(v.z); o.w = f2bf(v.w);
        *(ushort4*)&d[(size_t)n * 128 + j0] = o;
    }
}

// ---------- K1: router + Ag/Au projections (f32, split-K) + x->bf16 ----------
__global__ __launch_bounds__(256) void k_router(
    const float* __restrict__ x, const float* __restrict__ Wr,
    const float* __restrict__ Ag, const float* __restrict__ Au,
    u16* __restrict__ x16, float* __restrict__ fin1)
{
    __shared__ float xs[64][65];
    __shared__ float wsm[40][64];
    const int rb = blockIdx.x, ksp = blockIdx.y;
    const int row0 = rb * 64;
    const int t = threadIdx.x;
    const int rloc = t & 63, og = t >> 6;
    float acc[10];
#pragma unroll
    for (int o = 0; o < 10; ++o) acc[o] = 0.f;

    for (int c4 = 0; c4 < 4; ++c4) {
        const int k0 = ksp * 256 + c4 * 64;
        __syncthreads();
#pragma unroll
        for (int i = 0; i < 4; ++i) {
            int idx = t + i * 256;
            int r = idx >> 4, c = (idx & 15) * 4;
            float4 v = *(const float4*)&x[(size_t)(row0 + r) * 2048 + k0 + c];
            xs[r][c + 0] = v.x; xs[r][c + 1] = v.y; xs[r][c + 2] = v.z; xs[r][c + 3] = v.w;
            ushort4 o; o.x = f2bf(v.x); o.y = f2bf(v.y); o.z = f2bf(v.z); o.w = f2bf(v.w);
            *(ushort4*)&x16[(size_t)(row0 + r) * 2048 + k0 + c] = o;
        }
#pragma unroll
        for (int i = 0; i < 3; ++i) {
            int idx = t + i * 256;
            if (idx < 640) {
                int r = idx >> 4, c = (idx & 15) * 4;
                const float* src = (r < 8) ? (Wr + (size_t)r * 2048)
                                : (r < 24) ? (Ag + (size_t)(r - 8) * 2048)
                                           : (Au + (size_t)(r - 24) * 2048);
                float4 v = *(const float4*)&src[k0 + c];
                wsm[r][c + 0] = v.x; wsm[r][c + 1] = v.y; wsm[r][c + 2] = v.z; wsm[r][c + 3] = v.w;
            }
        }
        __syncthreads();
#pragma unroll
        for (int k = 0; k < 64; ++k) {
            float xv = xs[rloc][k];
#pragma unroll
            for (int o = 0; o < 10; ++o) acc[o] += xv * wsm[og * 10 + o][k];
        }
    }
    float* dst = fin1 + ((size_t)ksp * 4096 + row0 + rloc) * 40 + og * 10;
#pragma unroll
    for (int o = 0; o < 10; ++o) dst[o] = acc[o];
}

// ---------- K1b: softmax/argmax/expert_choice + hwg/hwu ----------
__global__ __launch_bounds__(64) void k_fin1(
    const float* __restrict__ fin1, const float* __restrict__ br,
    float* __restrict__ routing_ws, float* __restrict__ out_rt, float* __restrict__ out_ec,
    u16* __restrict__ hwg, u16* __restrict__ hwu)
{
    const int row = blockIdx.x * 64 + threadIdx.x;
    float s[40];
#pragma unroll
    for (int j = 0; j < 40; ++j) s[j] = 0.f;
    for (int p = 0; p < 8; ++p) {
        const float* src = fin1 + ((size_t)p * 4096 + row) * 40;
#pragma unroll
        for (int j = 0; j < 40; ++j) s[j] += src[j];
    }
    float lg[8]; float m = -1e30f;
#pragma unroll
    for (int e = 0; e < 8; ++e) { lg[e] = s[e] + br[e]; m = fmaxf(m, lg[e]); }
    float ex[8]; float sum = 0.f;
#pragma unroll
    for (int e = 0; e < 8; ++e) { ex[e] = expf(lg[e] - m); sum += ex[e]; }
    float r8[8];
#pragma unroll
    for (int e = 0; e < 8; ++e) r8[e] = ex[e] / sum;
    int best = 0;
#pragma unroll
    for (int e = 1; e < 8; ++e) if (r8[e] > r8[best]) best = e;
#pragma unroll
    for (int e = 0; e < 8; ++e) {
        routing_ws[(size_t)row * 8 + e] = r8[e];
        out_rt[(size_t)row * 8 + e] = r8[e];
        float yh = (e == best) ? 1.f : 0.f;
        out_ec[(size_t)row * 8 + e] = (yh - r8[e]) + r8[e];
    }
#pragma unroll
    for (int e = 0; e < 8; ++e) {
        float re = r8[e];
#pragma unroll
        for (int rk = 0; rk < 16; ++rk) {
            hwg[(size_t)row * 128 + e * 16 + rk] = f2bf(2.f * s[8 + rk] * re);
            hwu[(size_t)row * 128 + e * 16 + rk] = f2bf(2.f * s[24 + rk] * re);
        }
    }
}

// ---------- 256x256 GEMM (r6 schedule, direct-store epilogues) ----------
// C = A[*,K] @ B[*,K]^T. MODE 0 (down): z = K-split; f32 out. MODE 1: z = gate|up; bf16 out.
// LDS (u16 idx): A buf0 @0, buf1 @16384; B buf0 @32768, buf1 @49152.
// Swizzle: global[r][c] stored at LDS[r][c ^ ((r&7)<<3)] (u16), via pre-swizzled source col.
template<int MODE>
__global__ __launch_bounds__(512, 2) void k_gemm8(
    const u16* __restrict__ A0, int lda0,
    const u16* __restrict__ A1g, const u16* __restrict__ A1u,
    const u16* __restrict__ B0g, int ldb0, const u16* __restrict__ B0u,
    const u16* __restrict__ B1g, const u16* __restrict__ B1u,
    int Ksplit,
    float* __restrict__ outF0, float* __restrict__ outF1,
    u16* __restrict__ outHg, u16* __restrict__ outHu,
    int nbm, int nbn)
{
    __shared__ u16 lds[65536];   // 128 KiB
    const int t = threadIdx.x;
    const int nwg = (int)gridDim.x;
    const int orig = (int)blockIdx.x;
    const int sw = (orig & 7) * (nwg >> 3) + (orig >> 3);   // XCD swizzle (nwg%8==0)
    const int bm = sw % nbm; const int rest = sw / nbm;
    const int bn = rest % nbn; const int z = rest / nbn;

    const int row0 = bm * 256, col0 = bn * 256;
    int ktb, ntl;
    if (MODE == 0) { ktb = z ? 46 : 0; ntl = z ? 44 : 46; }  // ktb even, ntl even
    else           { ktb = 0;          ntl = 34; }
    const int kend = ktb + ntl;
    const u16* A1 = (MODE == 1 && z) ? A1u : A1g;
    const u16* B0 = (MODE == 1 && z) ? B0u : B0g;
    const u16* B1 = (MODE == 1 && z) ? B1u : B1g;

    const int lane = t & 63, lr = lane & 15, lg = lane >> 4;
    const int wid = t >> 6, wr = wid >> 2, wcol = wid & 3;
    const int arow = wr * 128 + lr;          // + fm*16
    const int brow = wcol * 64 + lr;         // + fn*16
    const int sa = (arow & 7) << 3;          // read-swizzle XOR (u16 units)
    const int sb = (brow & 7) << 3;

    // ---- staging: per-thread bases computed ONCE; per-call offset is wave-uniform ----
    const int rA = t >> 3;                                  // staging row-in-tile (h=0,j=0)
    const int c00u = ((t & 7) * 8) ^ ((rA & 7) << 3);       // pre-swizzled col (u16)
    const u16* bA0 = A0 + (size_t)(row0 + rA) * lda0 + c00u;
    const u16* bA1 = A1 + ((size_t)(row0 + rA) << 7) + c00u;
    const u16* bB0 = B0 + (size_t)(col0 + rA) * ldb0 + c00u;
    const u16* bB1 = B1 + ((size_t)(col0 + rA) << 7) + c00u;
    const int ldsT = t * 8;                                 // u16 units

    auto stgA = [&](int kt, int h, int bufu) {   // h, bufu literal at call sites
        const int k0 = kt * 64;
        const bool p2 = (k0 >= Ksplit);
        const u16* b = p2 ? (bA1 + (k0 - Ksplit)) : (bA0 + k0);
        const size_t ld = p2 ? (size_t)128 : (size_t)lda0;
        g2l16(b + (size_t)(h * 128) * ld,      &lds[bufu + h * 8192 + ldsT]);
        g2l16(b + (size_t)(h * 128 + 64) * ld, &lds[bufu + h * 8192 + 4096 + ldsT]);
    };
    auto stgB = [&](int kt, int h, int bufu) {
        const int k0 = kt * 64;
        const bool p2 = (k0 >= Ksplit);
        const u16* b = p2 ? (bB1 + (k0 - Ksplit)) : (bB0 + k0);
        const size_t ld = p2 ? (size_t)128 : (size_t)ldb0;
        g2l16(b + (size_t)(h * 128) * ld,      &lds[32768 + bufu + h * 8192 + ldsT]);
        g2l16(b + (size_t)(h * 128 + 64) * ld, &lds[32768 + bufu + h * 8192 + 4096 + ldsT]);
    };
    auto rdA = [&](int bufu, int fb, bf16x8 (&d)[4][2]) {
#pragma unroll
        for (int fm = 0; fm < 4; ++fm)
#pragma unroll
            for (int ks = 0; ks < 2; ++ks)
                d[fm][ks] = *(const bf16x8*)&lds[bufu + (arow + (fb + fm) * 16) * 64
                                                 + (((ks << 5) | (lg << 3)) ^ sa)];
    };
    auto rdB = [&](int bufu, int fb, bf16x8 (&d)[2][2]) {
#pragma unroll
        for (int fn = 0; fn < 2; ++fn)
#pragma unroll
            for (int ks = 0; ks < 2; ++ks)
                d[fn][ks] = *(const bf16x8*)&lds[32768 + bufu + (brow + (fb + fn) * 16) * 64
                                                 + (((ks << 5) | (lg << 3)) ^ sb)];
    };

    f32x4 acc[8][4];
    const f32x4 zf = {0.f, 0.f, 0.f, 0.f};
#pragma unroll
    for (int i = 0; i < 8; ++i)
#pragma unroll
        for (int j = 0; j < 4; ++j) acc[i][j] = zf;

    // prologue: A(ktb),B(ktb) -> buf0; B(ktb+1) -> buf1
    stgA(ktb, 0, 0); stgA(ktb, 1, 0);
    stgB(ktb, 0, 0); stgB(ktb, 1, 0);
    stgB(ktb + 1, 0, 16384); stgB(ktb + 1, 1, 16384);
    WAITV(4);              // buf0 landed; B(ktb+1) (4 loads) in flight
    BAR();

    const int ni = ntl >> 1;
    for (int i = 0; i < ni; ++i) {
        const int kt0 = ktb + 2 * i, kt1 = kt0 + 1;
        const bool s2 = (kt0 + 2 < kend), s3 = (kt1 + 2 < kend);  // TT or FF (ntl even)
        bf16x8 alo[4][2], ahi[4][2], b01[2][2], b23[2][2];
        // R1: Q0+Q1 of kt0 (buf0) | stage A(kt1)->buf1
        rdA(0, 0, alo); rdB(0, 0, b01); rdB(0, 2, b23);
        stgA(kt1, 0, 16384); stgA(kt1, 1, 16384);
        BAR();
        MM16(alo, b01, 0, 0); MM16(alo, b23, 0, 2);
        BAR();
        // R2: Q2+Q3 of kt0 | stage B(kt0+2)->buf0 | end: wait buf1 (B kt1 + A kt1) landed
        rdA(0, 4, ahi);
        if (s2) { stgB(kt0 + 2, 0, 0); stgB(kt0 + 2, 1, 0); }
        BAR();
        MM16(ahi, b01, 4, 0); MM16(ahi, b23, 4, 2);
        if (s2) { WAITV(4); } else { WAITV(0); }
        BAR();
        // R3: Q0+Q1 of kt1 (buf1) | stage A(kt0+2)->buf0
        rdA(16384, 0, alo); rdB(16384, 0, b01); rdB(16384, 2, b23);
        if (s2) { stgA(kt0 + 2, 0, 0); stgA(kt0 + 2, 1, 0); }
        BAR();
        MM16(alo, b01, 0, 0); MM16(alo, b23, 0, 2);
        BAR();
        // R4: Q2+Q3 of kt1 | stage B(kt1+2)->buf1 | end: wait buf0 (B,A of kt0+2) landed
        rdA(16384, 4, ahi);
        if (s3) { stgB(kt1 + 2, 0, 16384); stgB(kt1 + 2, 1, 16384); }
        BAR();
        MM16(ahi, b01, 4, 0); MM16(ahi, b23, 4, 2);
        if (s3) { WAITV(4); }
        BAR();
    }

    // epilogue: C/D layout col = lane&15, row = (lane>>4)*4 + j  [m89-verified]
#pragma unroll
    for (int fm = 0; fm < 8; ++fm) {
#pragma unroll
        for (int fn = 0; fn < 4; ++fn) {
            const int r = row0 + wr * 128 + fm * 16 + lg * 4;
            const int c = col0 + wcol * 64 + fn * 16 + lr;
            f32x4 v = acc[fm][fn];
            if constexpr (MODE == 0) {
                float* out = z ? outF1 : outF0;
#pragma unroll
                for (int j = 0; j < 4; ++j) out[(size_t)(r + j) * 2048 + c] = v[j];
            } else {
                u16* out = z ? outHu : outHg;
#pragma unroll
                for (int j = 0; j < 4; ++j) out[(size_t)(r + j) * 5632 + c] = f2bf(v[j]);
            }
        }
    }
}

// ---------- K5: fused SwiGLU + hd projection ----------
__global__ __launch_bounds__(256) void k_hd(
    u16* __restrict__ g, const u16* __restrict__ u,
    const float* __restrict__ Ad, float* __restrict__ fin2)
{
    __shared__ float hs[64][65];
    __shared__ float as2[16][64];
    const int rb = blockIdx.x, ksp = blockIdx.y;
    const int row0 = rb * 64;
    const int t = threadIdx.x;
    const int rloc = t & 63, og = t >> 6;
    float acc[4] = {0.f, 0.f, 0.f, 0.f};
    for (int c4 = 0; c4 < 8; ++c4) {
        const int k0 = ksp * 512 + c4 * 64;
        __syncthreads();
#pragma unroll
        for (int i = 0; i < 4; ++i) {
            int idx = t + i * 256;
            int r = idx >> 4, cc = (idx & 15) * 4;
            size_t go = (size_t)(row0 + r) * 5632 + k0 + cc;
            ushort4 gv = *(const ushort4*)&g[go];
            ushort4 uv = *(const ushort4*)&u[go];
            float h0, h1, h2, h3;
            { float gg = bf2f(gv.x); h0 = gg / (1.f + __expf(-gg)) * bf2f(uv.x); }
            { float gg = bf2f(gv.y); h1 = gg / (1.f + __expf(-gg)) * bf2f(uv.y); }
            { float gg = bf2f(gv.z); h2 = gg / (1.f + __expf(-gg)) * bf2f(uv.z); }
            { float gg = bf2f(gv.w); h3 = gg / (1.f + __expf(-gg)) * bf2f(uv.w); }
            hs[r][cc + 0] = h0; hs[r][cc + 1] = h1; hs[r][cc + 2] = h2; hs[r][cc + 3] = h3;
            ushort4 hv; hv.x = f2bf(h0); hv.y = f2bf(h1); hv.z = f2bf(h2); hv.w = f2bf(h3);
            *(ushort4*)&g[go] = hv;   // h overwrites gate (block-local 1:1, safe)
        }
        {
            int r = t >> 4, cc = (t & 15) * 4;
            float4 w = *(const float4*)&Ad[(size_t)r * 5632 + k0 + cc];
            as2[r][cc + 0] = w.x; as2[r][cc + 1] = w.y; as2[r][cc + 2] = w.z; as2[r][cc + 3] = w.w;
        }
        __syncthreads();
#pragma unroll
        for (int k = 0; k < 64; ++k) {
            float hv = hs[rloc][k];
#pragma unroll
            for (int o = 0; o < 4; ++o) acc[o] += hv * as2[og * 4 + o][k];
        }
    }
    float* dst = fin2 + ((size_t)ksp * 4096 + row0 + rloc) * 16 + og * 4;
#pragma unroll
    for (int o = 0; o < 4; ++o) dst[o] = acc[o];
}

// ---------- K5b: hwd = 2 * hd ⊗ routing (bf16) ----------
__global__ __launch_bounds__(64) void k_fin2(
    const float* __restrict__ fin2, const float* __restrict__ routing_ws, u16* __restrict__ hwd)
{
    const int row = blockIdx.x * 64 + threadIdx.x;
    float hd[16];
#pragma unroll
    for (int j = 0; j < 16; ++j) hd[j] = 0.f;
    for (int p = 0; p < 11; ++p) {
        const float* src = fin2 + ((size_t)p * 4096 + row) * 16;
#pragma unroll
        for (int j = 0; j < 16; ++j) hd[j] += src[j];
    }
#pragma unroll
    for (int e = 0; e < 8; ++e) {
        float re = routing_ws[(size_t)row * 8 + e];
#pragma unroll
        for (int rk = 0; rk < 16; ++rk)
            hwd[(size_t)row * 128 + e * 16 + rk] = f2bf(2.f * hd[rk] * re);
    }
}

// ---------- K7: out += split-K partial ----------
__global__ __launch_bounds__(256) void k_reduce(
    float* __restrict__ o, const float* __restrict__ p1)
{
    size_t i = ((size_t)blockIdx.x * 256 + threadIdx.x) * 4;
    float4 a = *(const float4*)&o[i];
    float4 b = *(const float4*)&p1[i];
    float4 r; r.x = a.x + b.x; r.y = a.y + b.y; r.z = a.z + b.z; r.w = a.w + b.w;
    *(float4*)&o[i] = r;
}

// ---------- launch ----------
extern "C" void kernel_launch(void* const* d_in, const int* in_sizes, int n_in,
                              void* d_out, int out_size, void* d_ws, size_t ws_size,
                              hipStream_t stream)
{
    (void)in_sizes; (void)n_in; (void)out_size; (void)ws_size;
    const float* x  = (const float*)d_in[0];
    const float* Wr = (const float*)d_in[1];
    const float* br = (const float*)d_in[2];
    const float* Wg = (const float*)d_in[3];
    const float* Wu = (const float*)d_in[4];
    const float* Wd = (const float*)d_in[5];
    const float* Ag = (const float*)d_in[6];
    const float* Au = (const float*)d_in[7];
    const float* Ad = (const float*)d_in[8];
    const float* Bg = (const float*)d_in[9];
    const float* Bu = (const float*)d_in[10];
    const float* Bd = (const float*)d_in[11];

    float* outp   = (float*)d_out;            // [4096, 2048]
    float* out_rt = outp + 8388608;           // [4096, 8]
    float* out_ec = out_rt + 32768;           // [4096, 8]

    char* p = (char*)d_ws;
    auto carve = [&](size_t n) -> char* { char* r = p; p += (n + 255) & ~(size_t)255; return r; };
    u16*   x16        = (u16*)carve(16777216);   // [4096,2048] bf16
    u16*   hwg        = (u16*)carve(1048576);    // [4096,128]
    u16*   hwu        = (u16*)carve(1048576);
    u16*   hwd        = (u16*)carve(1048576);
    float* routing_ws = (float*)carve(131072);   // [4096,8]
    float* fin1       = (float*)carve(5242880);  // [8][4096][40]
    float* fin2       = (float*)carve(2883584);  // [11][4096][16]
    u16*   Wg16       = (u16*)carve(23068672);   // [5632,2048]
    u16*   Wu16       = (u16*)carve(23068672);
    u16*   Wd16      = (u16*)carve(23068672);    // [2048,5632]
    u16*   Bgx        = (u16*)carve(1441792);    // [5632,128]
    u16*   Bux        = (u16*)carve(1441792);
    u16*   Bdx        = (u16*)carve(524288);     // [2048,128]
    u16*   gbuf       = (u16*)carve(46137344);   // [4096,5632] gate -> h (in place)
    u16*   ubuf       = (u16*)carve(46137344);   // [4096,5632] up; later f32 partial
    float* part1      = (float*)ubuf;            // [4096,2048] f32 split-K partial (aliases ubuf)

    k_conv<<<dim3(35456), dim3(256), 0, stream>>>(Wg, Wu, Wd, Bg, Bu, Bd,
                                                  Wg16, Wu16, Wd16, Bgx, Bux, Bdx);
    k_router<<<dim3(64, 8), dim3(256), 0, stream>>>(x, Wr, Ag, Au, x16, fin1);
    k_fin1<<<dim3(64), dim3(64), 0, stream>>>(fin1, br, routing_ws, out_rt, out_ec, hwg, hwu);
    // gate|up: C[z] = [x|hw z] @ [W z|B z]^T, K = 2048+128, 16x22x2 = 704 blocks
    k_gemm8<1><<<dim3(704), dim3(512), 0, stream>>>(
        x16, 2048, hwg, hwu, Wg16, 2048, Wu16, Bgx, Bux,
        2048, (float*)nullptr, (float*)nullptr, gbuf, ubuf, 16, 22);
    k_hd<<<dim3(64, 11), dim3(256), 0, stream>>>(gbuf, ubuf, Ad, fin2);
    k_fin2<<<dim3(64), dim3(64), 0, stream>>>(fin2, routing_ws, hwd);
    // down: out = [h|hwd] @ [Wd|Bdx]^T, K = 5632+128, split-K z: 46/44 tiles, 256 blocks
    k_gemm8<0><<<dim3(256), dim3(512), 0, stream>>>(
        gbuf, 5632, hwd, hwd, Wd16, 5632, Wd16, Bdx, Bdx,
        5632, outp, part1, (u16*)nullptr, (u16*)nullptr, 16, 8);
    k_reduce<<<dim3(8192), dim3(256), 0, stream>>>(outp, part1);
}